// Round 2
// baseline (1509.415 us; speedup 1.0000x reference)
//
#include <hip/hip_runtime.h>
#include <math.h>

// ============================================================================
// LegalMultiHeadAttention — B=2, S=4096, D_MODEL=1024, H=4, DK=256
// Round 2 strategy: split-bf16 (hi+lo) MFMA for ALL GEMMs.
//   x = hi + lo (bf16 truncation pair) -> A*B ~= Ah*Bh + Ah*Bl + Al*Bh
//   3x mfma_f32_16x16x32_bf16 per fragment, fp32 accumulate: ~fp32 accuracy.
// Uniform GEMM: A fp32 row-major (reg-staged + split into LDS),
//               B pre-transposed bf16 hi/lo [N][K] (global_load_lds width-16).
// Pipeline: transpose-convert weights -> Q/K/V projections -> transpose V ->
//           scores (NT) -> softmax -> PV -> out-proj.
// ============================================================================

constexpr int HN  = 4;
constexpr int BB  = 2;
constexpr int SS  = 4096;
constexpr int DM  = 1024;
constexpr int DKk = 256;
constexpr int BSr = BB * SS;   // 8192

typedef __bf16 v8bf __attribute__((ext_vector_type(8)));
typedef float  v4f  __attribute__((ext_vector_type(4)));

__device__ __forceinline__ void split2(float x, unsigned short& h, unsigned short& l) {
    unsigned xb = __float_as_uint(x);
    h = (unsigned short)(xb >> 16);                       // truncated bf16 (hi)
    float r = x - __uint_as_float(xb & 0xffff0000u);      // exact residual
    l = (unsigned short)(__float_as_uint(r) >> 16);       // truncated bf16 (lo)
}

// async global->LDS, 16B per lane, wave-uniform LDS base (lane scatters +16*l)
__device__ __forceinline__ void llds16(const unsigned short* g, unsigned short* l) {
    __builtin_amdgcn_global_load_lds(
        (const __attribute__((address_space(1))) unsigned int*)(const void*)g,
        (__attribute__((address_space(3))) unsigned int*)(void*)l, 16, 0, 0);
}

// ---------------------------------------------------------------------------
// Batched transpose + split-convert: in [z][R][C] f32 -> out hi/lo [z][C][R] bf16
// ---------------------------------------------------------------------------
__global__ __launch_bounds__(256)
void transpose_cvt(const float* __restrict__ in, unsigned short* __restrict__ ohi,
                   unsigned short* __restrict__ olo, int R, int C)
{
    __shared__ float t[32][33];
    const int z = blockIdx.z;
    const size_t zoff = (size_t)z * R * C;
    const int j  = threadIdx.x & 31;
    const int i0 = threadIdx.x >> 5;       // 0..7
    const int r0 = blockIdx.y * 32, c0 = blockIdx.x * 32;
    #pragma unroll
    for (int k = 0; k < 4; ++k)
        t[i0 + k * 8][j] = in[zoff + (size_t)(r0 + i0 + k * 8) * C + c0 + j];
    __syncthreads();
    #pragma unroll
    for (int k = 0; k < 4; ++k) {
        float v = t[j][i0 + k * 8];
        unsigned short h, l; split2(v, h, l);
        size_t o = zoff + (size_t)(c0 + i0 + k * 8) * R + r0 + j;
        ohi[o] = h; olo[o] = l;
    }
}

// ---------------------------------------------------------------------------
// Split-bf16 MFMA GEMM.  C = A * Bt^T (+bias) (*scale)
//   A: fp32 [M][K] row-major.  Bt: bf16 hi/lo [N][K] (k-contiguous). LDB == KD.
// MODE 0: projection  M=8192 N=256  K=1024 (z=head; B/bias/C offset by z)
// MODE 1: scores      M=4096 N=4096 K=256  (z=h*2+b), scale=1/16
// MODE 2: PV          M=4096 N=256  K=4096 (z=h*2+b), C scattered into concat
// MODE 3: out-proj    M=8192 N=1024 K=1024
// EPI 0: fp32 C.  EPI 1: dual bf16 hi/lo C (used for K-hat).
// ---------------------------------------------------------------------------
#define TBM 128
#define TBN 128
#define TBK 32

template<int MODE, int EPI>
__global__ __launch_bounds__(256, 2)
void mgemm(const float* __restrict__ Ab, const unsigned short* __restrict__ Bhb,
           const unsigned short* __restrict__ Blb, const float* __restrict__ biasb,
           float* __restrict__ Cf, unsigned short* __restrict__ Chi,
           unsigned short* __restrict__ Clo)
{
    constexpr int KD  = (MODE == 0 ? DM : MODE == 1 ? DKk : MODE == 2 ? SS : DM);
    constexpr int LDA = KD;                       // A is [M][KD] row-major in all modes
    constexpr int LDB = KD;                       // Bt is [N][KD]
    constexpr int LDC = (MODE == 0 ? DKk : MODE == 1 ? SS : MODE == 2 ? DM : DM);
    constexpr bool HAS_BIAS = (MODE == 0 || MODE == 3);
    constexpr float SCALE = (MODE == 1) ? 0.0625f : 1.0f;

    const int z = blockIdx.z;
    const float* A = Ab;
    const unsigned short* Bh_p = Bhb;
    const unsigned short* Bl_p = Blb;
    const float* bias = biasb;
    size_t coff = 0;
    if constexpr (MODE == 0) {
        Bh_p = Bhb + (size_t)z * DKk * DM;
        Bl_p = Blb + (size_t)z * DKk * DM;
        bias = biasb + (size_t)z * DKk;
        coff = (size_t)z * BSr * DKk;
    } else if constexpr (MODE == 1) {
        A    = Ab  + (size_t)z * SS * DKk;
        Bh_p = Bhb + (size_t)z * SS * DKk;
        Bl_p = Blb + (size_t)z * SS * DKk;
        coff = (size_t)z * SS * SS;
    } else if constexpr (MODE == 2) {
        A    = Ab  + (size_t)z * SS * SS;
        Bh_p = Bhb + (size_t)z * DKk * SS;
        Bl_p = Blb + (size_t)z * DKk * SS;
        coff = (size_t)(z & 1) * SS * DM + (size_t)(z >> 1) * DKk;
    }

    __shared__ alignas(16) unsigned short Ah[TBM][TBK];
    __shared__ alignas(16) unsigned short Al[TBM][TBK];
    __shared__ alignas(16) unsigned short Bh[TBN][TBK];
    __shared__ alignas(16) unsigned short Bl[TBN][TBK];

    const int tid  = threadIdx.x;
    const int lane = tid & 63;
    const int wave = tid >> 6;
    const int wm = wave >> 1, wn = wave & 1;      // 64x64 quadrant per wave
    const int fr = lane & 15, g = lane >> 4;      // fragment row / k-group
    const int m0 = blockIdx.y * TBM, n0 = blockIdx.x * TBN;
    const int ar = tid >> 1, ak = (tid & 1) * 16; // A staging: row, k-half
    const int br = lane >> 2, bk = (lane & 3) * 8;// B chunk lane mapping

    v4f acc[4][4];
    #pragma unroll
    for (int i = 0; i < 4; ++i)
        #pragma unroll
        for (int j = 0; j < 4; ++j) acc[i][j] = (v4f){0.f, 0.f, 0.f, 0.f};

    const float* aprow = A + (size_t)(m0 + ar) * LDA + ak;

    for (int kt = 0; kt < KD / TBK; ++kt) {
        const int k0 = kt * TBK;
        __syncthreads();   // previous iteration's reads complete before overwrite

        // ---- B tiles: async global->LDS (2 chunks per plane per wave) ----
        {
            const int c0c = wave * 2, c1c = wave * 2 + 1;
            const size_t r0c = (size_t)(n0 + c0c * 16 + br) * LDB + k0 + bk;
            const size_t r1c = (size_t)(n0 + c1c * 16 + br) * LDB + k0 + bk;
            llds16(Bh_p + r0c, &Bh[c0c * 16][0]);
            llds16(Bh_p + r1c, &Bh[c1c * 16][0]);
            llds16(Bl_p + r0c, &Bl[c0c * 16][0]);
            llds16(Bl_p + r1c, &Bl[c1c * 16][0]);
        }
        // ---- A tile: fp32 load, split, LDS store (16 floats/thread) ----
        {
            const float* ap = aprow + k0;
            const float4 v0 = *reinterpret_cast<const float4*>(ap + 0);
            const float4 v1 = *reinterpret_cast<const float4*>(ap + 4);
            const float4 v2 = *reinterpret_cast<const float4*>(ap + 8);
            const float4 v3 = *reinterpret_cast<const float4*>(ap + 12);
            const float f[16] = {v0.x, v0.y, v0.z, v0.w, v1.x, v1.y, v1.z, v1.w,
                                 v2.x, v2.y, v2.z, v2.w, v3.x, v3.y, v3.z, v3.w};
            unsigned int hw[8], lw[8];
            #pragma unroll
            for (int p = 0; p < 8; ++p) {
                unsigned short h0, l0, h1, l1;
                split2(f[2 * p], h0, l0);
                split2(f[2 * p + 1], h1, l1);
                hw[p] = (unsigned int)h0 | ((unsigned int)h1 << 16);
                lw[p] = (unsigned int)l0 | ((unsigned int)l1 << 16);
            }
            *reinterpret_cast<uint4*>(&Ah[ar][ak])     = make_uint4(hw[0], hw[1], hw[2], hw[3]);
            *reinterpret_cast<uint4*>(&Ah[ar][ak + 8]) = make_uint4(hw[4], hw[5], hw[6], hw[7]);
            *reinterpret_cast<uint4*>(&Al[ar][ak])     = make_uint4(lw[0], lw[1], lw[2], lw[3]);
            *reinterpret_cast<uint4*>(&Al[ar][ak + 8]) = make_uint4(lw[4], lw[5], lw[6], lw[7]);
        }
        __syncthreads();   // drains vmcnt (global_load_lds) + lgkmcnt

        // ---- fragments + 3-term split MFMA ----
        v8bf fah[4], fal[4], fbh[4], fbl[4];
        #pragma unroll
        for (int mf = 0; mf < 4; ++mf) {
            fah[mf] = *reinterpret_cast<const v8bf*>(&Ah[wm * 64 + mf * 16 + fr][g * 8]);
            fal[mf] = *reinterpret_cast<const v8bf*>(&Al[wm * 64 + mf * 16 + fr][g * 8]);
        }
        #pragma unroll
        for (int nf = 0; nf < 4; ++nf) {
            fbh[nf] = *reinterpret_cast<const v8bf*>(&Bh[wn * 64 + nf * 16 + fr][g * 8]);
            fbl[nf] = *reinterpret_cast<const v8bf*>(&Bl[wn * 64 + nf * 16 + fr][g * 8]);
        }
        #pragma unroll
        for (int mf = 0; mf < 4; ++mf)
            #pragma unroll
            for (int nf = 0; nf < 4; ++nf) {
                v4f a = acc[mf][nf];
                a = __builtin_amdgcn_mfma_f32_16x16x32_bf16(fah[mf], fbh[nf], a, 0, 0, 0);
                a = __builtin_amdgcn_mfma_f32_16x16x32_bf16(fah[mf], fbl[nf], a, 0, 0, 0);
                a = __builtin_amdgcn_mfma_f32_16x16x32_bf16(fal[mf], fbh[nf], a, 0, 0, 0);
                acc[mf][nf] = a;
            }
    }

    // ---- epilogue: C/D layout col=lane&15, row=(lane>>4)*4+j ----
    #pragma unroll
    for (int mf = 0; mf < 4; ++mf) {
        const int rbase = m0 + wm * 64 + mf * 16 + g * 4;
        #pragma unroll
        for (int nf = 0; nf < 4; ++nf) {
            const int col = n0 + wn * 64 + nf * 16 + fr;
            float bb = 0.0f;
            if constexpr (HAS_BIAS) bb = bias[col];
            #pragma unroll
            for (int j = 0; j < 4; ++j) {
                const float v = acc[mf][nf][j] * SCALE + bb;
                const size_t idx = coff + (size_t)(rbase + j) * LDC + col;
                if constexpr (EPI == 0) {
                    Cf[idx] = v;
                } else {
                    unsigned short h, l; split2(v, h, l);
                    Chi[idx] = h; Clo[idx] = l;
                }
            }
        }
    }
}

// ---------------------------------------------------------------------------
// Row softmax over last dim (4096), in place. One 256-thread block per row.
// ---------------------------------------------------------------------------
__global__ __launch_bounds__(256)
void softmax_k(float* __restrict__ attn)
{
    const size_t row = blockIdx.x;
    float* p = attn + row * (size_t)SS;
    const int t = threadIdx.x;

    float4 v[4];
    #pragma unroll
    for (int i = 0; i < 4; ++i)
        v[i] = *reinterpret_cast<float4*>(p + t * 4 + i * 1024);

    float m = -3.4e38f;
    #pragma unroll
    for (int i = 0; i < 4; ++i)
        m = fmaxf(m, fmaxf(fmaxf(v[i].x, v[i].y), fmaxf(v[i].z, v[i].w)));
    #pragma unroll
    for (int off = 32; off > 0; off >>= 1) m = fmaxf(m, __shfl_xor(m, off));

    __shared__ float redm[4];
    __shared__ float reds[4];
    const int wid = t >> 6;
    if ((t & 63) == 0) redm[wid] = m;
    __syncthreads();
    m = fmaxf(fmaxf(redm[0], redm[1]), fmaxf(redm[2], redm[3]));

    float s = 0.0f;
    #pragma unroll
    for (int i = 0; i < 4; ++i) {
        v[i].x = __expf(v[i].x - m); s += v[i].x;
        v[i].y = __expf(v[i].y - m); s += v[i].y;
        v[i].z = __expf(v[i].z - m); s += v[i].z;
        v[i].w = __expf(v[i].w - m); s += v[i].w;
    }
    #pragma unroll
    for (int off = 32; off > 0; off >>= 1) s += __shfl_xor(s, off);
    if ((t & 63) == 0) reds[wid] = s;
    __syncthreads();
    s = reds[0] + reds[1] + reds[2] + reds[3];
    const float inv = 1.0f / s;

    #pragma unroll
    for (int i = 0; i < 4; ++i) {
        v[i].x *= inv; v[i].y *= inv; v[i].z *= inv; v[i].w *= inv;
        *reinterpret_cast<float4*>(p + t * 4 + i * 1024) = v[i];
    }
}

// ---------------------------------------------------------------------------
extern "C" void kernel_launch(void* const* d_in, const int* in_sizes, int n_in,
                              void* d_out, int out_size, void* d_ws, size_t ws_size,
                              hipStream_t stream)
{
    const float* query = (const float*)d_in[0];
    const float* keyi  = (const float*)d_in[1];
    const float* value = (const float*)d_in[2];
    const float* Wq    = (const float*)d_in[3];
    const float* bq    = (const float*)d_in[4];
    const float* Wk    = (const float*)d_in[5];
    const float* bk    = (const float*)d_in[6];
    const float* Wv    = (const float*)d_in[7];
    const float* bv    = (const float*)d_in[8];
    const float* Wo    = (const float*)d_in[9];
    const float* bo    = (const float*)d_in[10];

    float* out  = (float*)d_out;                  // [8192][1024]
    float* attn = out + (size_t)BSr * DM;         // [H][B][S][S] (post-softmax)

    // ---- workspace layout (151.0 MB total) ----
    char* w = (char*)d_ws;
    auto take = [&](size_t bytes) { char* p = w; w += bytes; return p; };
    const size_t WQKV_PL = (size_t)HN * DKk * DM * 2;    // 2 MB per plane
    const size_t WO_PL   = (size_t)DM * DM * 2;          // 2 MB
    const size_t QKV_E   = (size_t)HN * BSr * DKk;       // 8,388,608 elems

    unsigned short* Wqt_h = (unsigned short*)take(WQKV_PL);
    unsigned short* Wqt_l = (unsigned short*)take(WQKV_PL);
    unsigned short* Wkt_h = (unsigned short*)take(WQKV_PL);
    unsigned short* Wkt_l = (unsigned short*)take(WQKV_PL);
    unsigned short* Wvt_h = (unsigned short*)take(WQKV_PL);
    unsigned short* Wvt_l = (unsigned short*)take(WQKV_PL);
    unsigned short* Wot_h = (unsigned short*)take(WO_PL);
    unsigned short* Wot_l = (unsigned short*)take(WO_PL);
    float*          Qf    = (float*)take(QKV_E * 4);
    unsigned short* Kh    = (unsigned short*)take(QKV_E * 2);
    unsigned short* Kl    = (unsigned short*)take(QKV_E * 2);
    unsigned short* Vth   = (unsigned short*)take(QKV_E * 2);
    unsigned short* Vtl   = (unsigned short*)take(QKV_E * 2);
    float*          conc  = (float*)take(QKV_E * 4);
    // V fp32 staging lives in the attn region (overwritten later by scores)
    float* Vf = attn;

    const dim3 blk(256);

    // 1) weight transpose+convert: W[h][1024][256] -> Wt[h][256][1024] hi/lo
    transpose_cvt<<<dim3(DKk / 32, DM / 32, HN), blk, 0, stream>>>(Wq, Wqt_h, Wqt_l, DM, DKk);
    transpose_cvt<<<dim3(DKk / 32, DM / 32, HN), blk, 0, stream>>>(Wk, Wkt_h, Wkt_l, DM, DKk);
    transpose_cvt<<<dim3(DKk / 32, DM / 32, HN), blk, 0, stream>>>(Wv, Wvt_h, Wvt_l, DM, DKk);
    transpose_cvt<<<dim3(DM / 32, DM / 32, 1), blk, 0, stream>>>(Wo, Wot_h, Wot_l, DM, DM);

    // 2) projections (z = head): Q fp32; K dual-bf16; V fp32 (into attn region)
    mgemm<0, 0><<<dim3(DKk / TBN, BSr / TBM, HN), blk, 0, stream>>>(query, Wqt_h, Wqt_l, bq, Qf, nullptr, nullptr);
    mgemm<0, 1><<<dim3(DKk / TBN, BSr / TBM, HN), blk, 0, stream>>>(keyi, Wkt_h, Wkt_l, bk, nullptr, Kh, Kl);
    mgemm<0, 0><<<dim3(DKk / TBN, BSr / TBM, HN), blk, 0, stream>>>(value, Wvt_h, Wvt_l, bv, Vf, nullptr, nullptr);

    // 3) V-hat transpose: [z=h*2+b][4096][256] -> Vt[z][256][4096] hi/lo
    transpose_cvt<<<dim3(DKk / 32, SS / 32, HN * BB), blk, 0, stream>>>(Vf, Vth, Vtl, SS, DKk);

    // 4) scores: logits = Q K^T / 16 -> attn region
    mgemm<1, 0><<<dim3(SS / TBN, SS / TBM, HN * BB), blk, 0, stream>>>(Qf, Kh, Kl, nullptr, attn, nullptr, nullptr);

    // 5) softmax in place (also the attn output)
    softmax_k<<<dim3(HN * BB * SS), blk, 0, stream>>>(attn);

    // 6) PV: concat[b*4096+q][h*256+d]
    mgemm<2, 0><<<dim3(DKk / TBN, SS / TBM, HN * BB), blk, 0, stream>>>(attn, Vth, Vtl, nullptr, conc, nullptr, nullptr);

    // 7) output projection
    mgemm<3, 0><<<dim3(DM / TBN, BSr / TBM, 1), blk, 0, stream>>>(conc, Wot_h, Wot_l, bo, out, nullptr, nullptr);
}